// Round 12
// baseline (388.692 us; speedup 1.0000x reference)
//
#include <hip/hip_runtime.h>
#include <math.h>
#include <stdint.h>

// Problem constants: B=8, N=2048, D=512, H=16, dk=32
// q = x@Wq^T; k = x@Wk^T; v = x@Wv^T            [t=16384, c=512]
// dw[b,i,j] = exp(-alpha*11*dis[b,i,j])
// w1[b,j,c] = sum_i dw[b,i,j]*exp(k)[b,i,c]*v[b,i,c]
// w2[b,j,c] = sum_i dw[b,i,j]*exp(k)[b,i,c]
// out[b,j,c] = sigmoid(q)[b,j,c] * w1/w2
//
// Round-12: fused main_gemm keeps the r11 counted-vmcnt skeleton but fixes the
// dis FETCH PATTERN (r11's real bottleneck: 128-B scattered segments -> 750
// GB/s; 134 MB at 750 GB/s = 179 us = measured 184). Now one wave loads ONE
// dis row per instruction: 64 lanes x f32x4 = 1 KB contiguous. Transpose falls
// out in registers; A-LDS uses involution fA(j) = (j^(j>>3))&7 (thread's j's
// are 4*lane+c, so the old j&7 swizzle would collapse to 2 bank positions).

typedef __bf16 bf16_t;
typedef __attribute__((ext_vector_type(4))) __bf16 bf16x4;
typedef __attribute__((ext_vector_type(8))) __bf16 bf16x8;
typedef __attribute__((ext_vector_type(4))) float f32x4;

#define MFMA_BF16(a, b, c) __builtin_amdgcn_mfma_f32_16x16x32_bf16((a), (b), (c), 0, 0, 0)

static __device__ __forceinline__ void async_ld16(const bf16_t* g, bf16_t* lds) {
  __builtin_amdgcn_global_load_lds(
      reinterpret_cast<__attribute__((address_space(1))) unsigned int*>(
          reinterpret_cast<uintptr_t>(g)),
      reinterpret_cast<__attribute__((address_space(3))) unsigned int*>(
          reinterpret_cast<uintptr_t>(lds)),
      16, 0, 0);
}

// async f32x4 load via inline asm: ISSUES here (volatile), does NOT wait.
static __device__ __forceinline__ f32x4 async_ldg_f32x4(const float* p) {
  f32x4 r;
  asm volatile("global_load_dwordx4 %0, %1, off" : "=&v"(r) : "v"(p) : "memory");
  return r;
}

// counted-vmcnt wait (T4). sched_barrier stops hipcc hoisting dependents (rule #18).
#define WAITV(N)                                          \
  do {                                                    \
    asm volatile("s_waitcnt vmcnt(" #N ")" ::: "memory"); \
    __builtin_amdgcn_sched_barrier(0);                    \
  } while (0)

#define WAIT_LGKM0()                                        \
  do {                                                      \
    asm volatile("s_waitcnt lgkmcnt(0)" ::: "memory");      \
    __builtin_amdgcn_sched_barrier(0);                      \
  } while (0)

// ---- 3-bit XOR swizzle pair (hardware-validated rounds 3-11) ----
template <int ROWS>
static __device__ __forceinline__ void stage3(const bf16_t* g, int ldg, bf16_t* lds,
                                              int wv, int lane) {
  const int r_in = lane >> 3;      // 8 chunks per 64-wide row
  const int cpos = lane & 7;
#pragma unroll
  for (int s = 0; s < ROWS / 32; ++s) {
    int rbase = wv * (ROWS / 4) + s * 8;   // multiple of 8 -> row&7 == r_in
    int row = rbase + r_in;
    int cg = cpos ^ (row & 7);
    async_ld16(g + (size_t)row * ldg + cg * 8, lds + rbase * 64 + lane * 8);
  }
}

// Swizzled fragment read (BK=64), f(row)=row&7 (B path + proj).
static __device__ __forceinline__ bf16x8 frag3(const bf16_t* lds, int row16,
                                               int l15, int quad, int kc) {
  int p = (quad | (kc << 2)) ^ (l15 & 7);
  return *(const bf16x8*)&lds[(row16 + l15) * 64 + p * 8];
}

// A-path fragment read, fA(j) = (j ^ (j>>3)) & 7 (write side uses the same).
static __device__ __forceinline__ bf16x8 fragA(const bf16_t* lds, int row16,
                                               int l15, int quad, int kc) {
  int j = row16 + l15;
  int p = (quad | (kc << 2)) ^ ((j ^ (j >> 3)) & 7);
  return *(const bf16x8*)&lds[j * 64 + p * 8];
}

// ---------------- fused fp32 -> bf16 conversion ----------------
__global__ __launch_bounds__(256) void cvt_all(const float* __restrict__ x,
                                               const float* __restrict__ wq,
                                               const float* __restrict__ wk,
                                               const float* __restrict__ wv,
                                               bf16_t* __restrict__ xb,
                                               bf16_t* __restrict__ wall) {
  int i = blockIdx.x * 256 + threadIdx.x;  // f32x4 index
  if (i >= 2293760) return;
  const float* src;
  bf16_t* dst;
  int off;
  if (i < 2097152) {
    src = x; dst = xb; off = i;
  } else {
    int j = i - 2097152;
    int sel = j >> 16;        // 65536 f32x4 per weight
    off = j & 65535;
    src = (sel == 0) ? wq : (sel == 1) ? wk : wv;
    dst = wall + (size_t)sel * 262144;
  }
  f32x4 f = ((const f32x4*)src)[off];
  bf16x4 o;
  o[0] = (bf16_t)f[0]; o[1] = (bf16_t)f[1]; o[2] = (bf16_t)f[2]; o[3] = (bf16_t)f[3];
  ((bf16x4*)dst)[off] = o;
}

// ---------------- projection GEMM (proj-only) ----------------
// 1536 blocks: m_blk = idx/12 (0..127), n_blk = idx%12. Verified rounds 6-11.
__global__ __launch_bounds__(256, 4) void proj_dw(const bf16_t* __restrict__ A,
                                                  const bf16_t* __restrict__ W,
                                                  bf16_t* __restrict__ qs,
                                                  bf16_t* __restrict__ kwT,
                                                  bf16_t* __restrict__ kwvT) {
  __shared__ __align__(16) char pool[32768];
  const int tid = threadIdx.x;
  const int sub = blockIdx.x;
  const int m_blk = sub / 12, n_blk = sub % 12;
  bf16_t* As = (bf16_t*)pool;  // 128x64 = 16 KB
  const int K = 512;
  const int wv = tid >> 6, lane = tid & 63;
  const int l15 = lane & 15, quad = lane >> 4;
  const int wm = wv >> 1, wn = wv & 1;
  const bf16_t* Am = A + (size_t)(m_blk * 128) * K;
  const int b = m_blk >> 4;

  if (n_blk < 4) {
    // ---- q path: 128x128 tile, 64x64 wave tiles, BK=64 ----
    bf16_t* Bsq = (bf16_t*)(pool + 16384);  // 128x64 = 16 KB
    const int c_loc = n_blk * 128;
    f32x4 acc[4][4];
#pragma unroll
    for (int a = 0; a < 4; ++a)
#pragma unroll
      for (int c = 0; c < 4; ++c) acc[a][c] = (f32x4){0.f, 0.f, 0.f, 0.f};

    for (int k0 = 0; k0 < K; k0 += 64) {
      stage3<128>(Am + k0, K, As, wv, lane);
      stage3<128>(W + (size_t)c_loc * K + k0, K, Bsq, wv, lane);
      __syncthreads();
#pragma unroll
      for (int kc = 0; kc < 2; ++kc) {
        bf16x8 a[4], bb[4];
#pragma unroll
        for (int mf = 0; mf < 4; ++mf) a[mf] = frag3(As, wm * 64 + mf * 16, l15, quad, kc);
#pragma unroll
        for (int nf = 0; nf < 4; ++nf) bb[nf] = frag3(Bsq, wn * 64 + nf * 16, l15, quad, kc);
#pragma unroll
        for (int mf = 0; mf < 4; ++mf)
#pragma unroll
          for (int nf = 0; nf < 4; ++nf) acc[mf][nf] = MFMA_BF16(a[mf], bb[nf], acc[mf][nf]);
      }
      __syncthreads();
    }
#pragma unroll
    for (int mf = 0; mf < 4; ++mf)
#pragma unroll
      for (int nf = 0; nf < 4; ++nf) {
        int j16 = (m_blk & 15) * 8 + wm * 4 + mf;
        int c16 = n_blk * 8 + wn * 4 + nf;
        bf16x4 o;
#pragma unroll
        for (int r = 0; r < 4; ++r)
          o[r] = (bf16_t)(1.0f / (1.0f + __expf(-acc[mf][nf][r])));
        size_t off = (((size_t)b * 128 + j16) * 32 + c16) * 256 + quad * 64 + l15 * 4;
        *(bf16x4*)&qs[off] = o;
      }
  } else {
    // ---- kv path: 128x64 tile, 64x32 wave tiles, k and v share A staging, BK=64 ----
    bf16_t* Bk = (bf16_t*)(pool + 16384);  // 64x64 = 8 KB
    bf16_t* Bv = (bf16_t*)(pool + 24576);  // 64x64 = 8 KB
    const int c_loc = (n_blk - 4) * 64;
    f32x4 acck[4][2], accv[4][2];
#pragma unroll
    for (int a = 0; a < 4; ++a)
#pragma unroll
      for (int c = 0; c < 2; ++c) {
        acck[a][c] = (f32x4){0.f, 0.f, 0.f, 0.f};
        accv[a][c] = (f32x4){0.f, 0.f, 0.f, 0.f};
      }
    const bf16_t* Wk = W + (size_t)(512 + c_loc) * K;
    const bf16_t* Wv = W + (size_t)(1024 + c_loc) * K;

    for (int k0 = 0; k0 < K; k0 += 64) {
      stage3<128>(Am + k0, K, As, wv, lane);
      stage3<64>(Wk + k0, K, Bk, wv, lane);
      stage3<64>(Wv + k0, K, Bv, wv, lane);
      __syncthreads();
#pragma unroll
      for (int kc = 0; kc < 2; ++kc) {
        bf16x8 a[4], bk[2], bv[2];
#pragma unroll
        for (int mf = 0; mf < 4; ++mf) a[mf] = frag3(As, wm * 64 + mf * 16, l15, quad, kc);
#pragma unroll
        for (int nf = 0; nf < 2; ++nf) {
          bk[nf] = frag3(Bk, wn * 32 + nf * 16, l15, quad, kc);
          bv[nf] = frag3(Bv, wn * 32 + nf * 16, l15, quad, kc);
        }
#pragma unroll
        for (int mf = 0; mf < 4; ++mf)
#pragma unroll
          for (int nf = 0; nf < 2; ++nf) {
            acck[mf][nf] = MFMA_BF16(a[mf], bk[nf], acck[mf][nf]);
            accv[mf][nf] = MFMA_BF16(a[mf], bv[nf], accv[mf][nf]);
          }
      }
      __syncthreads();
    }

    // epilogue: exp/mul + 32-c-chunk transpose through aliased LDS
    bf16_t* Lk = (bf16_t*)pool;            // 32 x 136 = 8704 B
    bf16_t* Lv = (bf16_t*)(pool + 8704);   // 32 x 136 = 8704 B
    const int t0 = (m_blk * 128) & 2047;
#pragma unroll
    for (int ci = 0; ci < 2; ++ci) {
      if (wn == ci) {
#pragma unroll
        for (int mf = 0; mf < 4; ++mf)
#pragma unroll
          for (int nf = 0; nf < 2; ++nf) {
            int cl = nf * 16 + l15;
            int tl = wm * 64 + mf * 16 + quad * 4;
#pragma unroll
            for (int r = 0; r < 4; ++r) {
              float kw = __expf(acck[mf][nf][r]);
              Lk[cl * 136 + tl + r] = (bf16_t)kw;
              Lv[cl * 136 + tl + r] = (bf16_t)(kw * accv[mf][nf][r]);
            }
          }
      }
      __syncthreads();
      {
        int rowt = tid >> 3, colt = (tid & 7) * 16;
        int c = c_loc + ci * 32 + rowt;
        size_t g = ((size_t)b * 512 + c) * 2048 + t0 + colt;
        *(bf16x8*)&kwT[g] = *(const bf16x8*)&Lk[rowt * 136 + colt];
        *(bf16x8*)&kwT[g + 8] = *(const bf16x8*)&Lk[rowt * 136 + colt + 8];
        *(bf16x8*)&kwvT[g] = *(const bf16x8*)&Lv[rowt * 136 + colt];
        *(bf16x8*)&kwvT[g + 8] = *(const bf16x8*)&Lv[rowt * 136 + colt + 8];
      }
      __syncthreads();
    }
  }
}

// ---------------- main batched GEMM + FUSED dis->exp->transpose A-staging ----------------
// 256^2 / 8-wave (2M x 4N) / BK=64 / 4 phases / 2 x 64 KB LDS buffers.
// dis loads: wave wv reads rows t*64 + wv*8 + s (s=0..7), 64 lanes x f32x4 =
// 1 KB CONTIGUOUS per instruction (the r11 fix). Thread (wv,lane) holds rows
// wv*8..+7 x cols 4lane..+3 -> for each col j it owns i-chunk wv -> one
// ds_write_b128 at pos = wv ^ fA(j). Ledger (issue at P0: dis x8 then B x4):
//   entry: 2 carried (cb2,cb3 of t) | after issue: 14
//   P0-end WAITV(12) -> publish cb2,cb3(t)        (P1 reads b1)
//   P1-end WAITV(4)  -> all 8 dis retired          (P2/P3 convert)
//   P3    WAITV(2) + lgkmcnt(0) + s_barrier -> publish A(nx) + cb0,cb1(t+1);
//         cb2,cb3(t+1) stay in flight across the boundary.
__global__ __launch_bounds__(512, 2) void main_gemm(const float* __restrict__ dis,
                                                    const bf16_t* __restrict__ kwvT,
                                                    const bf16_t* __restrict__ kwT,
                                                    const bf16_t* __restrict__ qs,
                                                    const float* __restrict__ alpha,
                                                    float* __restrict__ out) {
  extern __shared__ __align__(16) char smem_raw[];
  bf16_t* const lds = (bf16_t*)smem_raw;  // [2 buf][A 16384 | B 16384] elements
  const int K = 2048;
  const int tid = threadIdx.x;
  const int wv = tid >> 6, lane = tid & 63;
  const int l15 = lane & 15, quad = lane >> 4;
  const int bi = blockIdx.x;
  const int b = bi & 7, nbb = (bi >> 3) & 3, mb = bi >> 5;
  const int wm = wv >> 2, wn = wv & 3;       // 2 m-waves x 4 n-waves
  const int r_in = lane >> 3, cpos = lane & 7;
  const int cg = cpos ^ r_in;                // B-path swizzled source chunk

  const float coef = -alpha[0] * 11.0f;      // log2(2048) == 11

  const bf16_t* const BvB = kwvT + (size_t)b * 512 * K;
  const bf16_t* const BkB = kwT + (size_t)b * 512 * K;

  // dis row-major base: col = mb*256 + lane*4 (16 B per lane, 1 KB per wave-row)
  const float* const disR = dis + (size_t)b * 2048 * 2048 + (size_t)(mb * 256 + lane * 4);

  // B chunks cb=0..3 = read-order quarters of the interleaved B rows (verified):
  const bf16_t* bSrc[4];
  int bDst[4];
#pragma unroll
  for (int cb = 0; cb < 4; ++cb) {
    const int base1 = (cb & 1) * 128 + (cb >> 1) * 32;
    const int rowbase = base1 + (wv >> 2) * 64 + (wv & 3) * 8;
    const int row = rowbase + r_in;            // row&7 == r_in (bases mult. of 8)
    const int type = (row >> 4) & 1;           // 0 -> kwv (w1), 1 -> kw (w2)
    const int crow = nbb * 128 + (row >> 5) * 16 + (row & 15);
    bSrc[cb] = (type ? BkB : BvB) + (size_t)crow * K + cg * 8;
    bDst[cb] = 16384 + rowbase * 64 + lane * 8;
  }

  f32x4 acc[8][4];
#pragma unroll
  for (int m = 0; m < 8; ++m)
#pragma unroll
    for (int n = 0; n < 4; ++n) acc[m][n] = (f32x4){0.f, 0.f, 0.f, 0.f};

  bf16x8 a[8];   // current A m-half: [mf*2+kc]
  bf16x8 b0[4];  // B n-half 0
  bf16x8 b1[4];  // B n-half 1
  f32x4 rA[8];   // in-flight dis rows wv*8+s, cols 4lane..+3 (static-indexed)

#define STAGE_B(dst, cb, koff) async_ld16(bSrc[cb] + (koff), lds + (dst)*32768 + bDst[cb])

// issue the 8 row-loads for tile tt (dis FIRST in the vmcnt FIFO)
#define ISSUE_DIS(tt)                                                              \
  do {                                                                             \
    const float* dp_ = disR + (size_t)((tt)*64 + wv * 8) * 2048;                   \
    _Pragma("unroll") for (int s_ = 0; s_ < 8; ++s_)                               \
        rA[s_] = async_ldg_f32x4(dp_ + (size_t)s_ * 2048);                         \
  } while (0)

// convert 2 columns (cbase, cbase+1): exp + pack 8 rows -> one b128 write each.
// A[j][i] stored: chunk wv at pos = wv ^ fA(j), fA(j) = (j^(j>>3))&7.
#define CONVW2(dstbuf, cbase)                                                      \
  do {                                                                             \
    bf16_t* An_ = lds + (dstbuf)*32768;                                            \
    _Pragma("unroll") for (int cc_ = 0; cc_ < 2; ++cc_) {                          \
      const int j_ = lane * 4 + (cbase) + cc_;                                     \
      bf16x8 w_;                                                                   \
      _Pragma("unroll") for (int s_ = 0; s_ < 8; ++s_)                             \
          w_[s_] = (bf16_t)__expf(coef * rA[s_][(cbase) + cc_]);                   \
      *(bf16x8*)&An_[j_ * 64 + ((wv ^ ((j_ ^ (j_ >> 3)) & 7)) << 3)] = w_;         \
    }                                                                              \
  } while (0)

#define LOADA(As_, mh)                                                             \
  do {                                                                             \
    _Pragma("unroll") for (int mf = 0; mf < 4; ++mf)                               \
        _Pragma("unroll") for (int kc = 0; kc < 2; ++kc)                           \
            a[mf * 2 + kc] =                                                       \
        fragA((As_), wm * 128 + (mh)*64 + mf * 16, l15, quad, kc);                 \
  } while (0)

#define LOADB(Bs_, dstarr, nh)                                                     \
  do {                                                                             \
    _Pragma("unroll") for (int nf = 0; nf < 2; ++nf)                               \
        _Pragma("unroll") for (int kc = 0; kc < 2; ++kc)                           \
            dstarr[nf * 2 + kc] =                                                  \
        frag3((Bs_), wn * 64 + (nh)*32 + nf * 16, l15, quad, kc);                  \
  } while (0)

#define MFMA_PH(mh, nh, barr)                                                      \
  do {                                                                             \
    __builtin_amdgcn_s_setprio(1);                                                 \
    _Pragma("unroll") for (int kc = 0; kc < 2; ++kc)                               \
        _Pragma("unroll") for (int mf = 0; mf < 4; ++mf)                           \
            _Pragma("unroll") for (int nf = 0; nf < 2; ++nf)                       \
                acc[(mh)*4 + mf][(nh)*2 + nf] =                                    \
        MFMA_BF16(a[mf * 2 + kc], barr[nf * 2 + kc], acc[(mh)*4 + mf][(nh)*2 + nf]); \
    __builtin_amdgcn_s_setprio(0);                                                 \
  } while (0)

  // prologue: tile 0 — dis first, then B; convert; publish cb0,cb1; carry cb2,cb3.
  ISSUE_DIS(0);
  STAGE_B(0, 0, 0); STAGE_B(0, 1, 0); STAGE_B(0, 2, 0); STAGE_B(0, 3, 0);
  WAITV(4);                 // retire dis(0) x8 -> 4 B outstanding
  CONVW2(0, 0);
  CONVW2(0, 2);
  WAITV(2);                 // retire cb0,cb1(0); cb2,cb3 stay in flight
  WAIT_LGKM0();             // CONVW ds_writes visible
  __builtin_amdgcn_s_barrier();

  for (int t = 0; t < 31; ++t) {
    const int c = t & 1;
    const int nx = c ^ 1;
    const bf16_t* As_c = lds + c * 32768;
    const bf16_t* Bs_c = As_c + 16384;
    const int ko = (t + 1) * 64;
    // P0: issue t+1 (dis x8 then B x4); read m0/b0; mfma (m0,n0); publish cb2,cb3(t)
    ISSUE_DIS(t + 1);
    STAGE_B(nx, 0, ko); STAGE_B(nx, 1, ko); STAGE_B(nx, 2, ko); STAGE_B(nx, 3, ko);
    LOADA(As_c, 0);
    LOADB(Bs_c, b0, 0);
    __builtin_amdgcn_s_barrier();
    MFMA_PH(0, 0, b0);
    WAITV(12);              // retire cb2,cb3(t)
    __builtin_amdgcn_s_barrier();
    // P1: read b1 (cb2,cb3(t), just published); mfma (m0,n1); dis arrives
    LOADB(Bs_c, b1, 1);
    __builtin_amdgcn_s_barrier();
    MFMA_PH(0, 1, b1);
    WAITV(4);               // retire all 8 dis(t+1)
    __builtin_amdgcn_s_barrier();
    // P2: convert cols 0,1 into nx; read m1; mfma (m1,n1)
    CONVW2(nx, 0);
    LOADA(As_c, 1);
    __builtin_amdgcn_s_barrier();
    MFMA_PH(1, 1, b1);
    __builtin_amdgcn_s_barrier();
    // P3: convert cols 2,3 into nx; mfma (m1,n0); counted boundary
    CONVW2(nx, 2);
    MFMA_PH(1, 0, b0);
    WAITV(2);               // retire cb0,cb1(t+1); cb2,cb3(t+1) stay in flight
    WAIT_LGKM0();           // CONVW ds_writes (P2+P3) visible
    __builtin_amdgcn_s_barrier();
  }

  // peeled t=31: no issues; WAITV(0) publishes cb2,cb3(31)
  {
    const bf16_t* As_c = lds + 32768;  // 31&1 = 1
    const bf16_t* Bs_c = As_c + 16384;
    LOADA(As_c, 0);
    LOADB(Bs_c, b0, 0);
    __builtin_amdgcn_s_barrier();
    MFMA_PH(0, 0, b0);
    WAITV(0);
    __builtin_amdgcn_s_barrier();
    LOADB(Bs_c, b1, 1);
    __builtin_amdgcn_s_barrier();
    MFMA_PH(0, 1, b1);
    __builtin_amdgcn_s_barrier();
    LOADA(As_c, 1);
    __builtin_amdgcn_s_barrier();
    MFMA_PH(1, 1, b1);
    __builtin_amdgcn_s_barrier();
    MFMA_PH(1, 0, b0);
  }

#undef STAGE_B
#undef ISSUE_DIS
#undef CONVW2
#undef LOADA
#undef LOADB
#undef MFMA_PH

  // epilogue: nf even = w1 (kwv), nf odd = w2 (kw); pair in registers.
#pragma unroll
  for (int mf = 0; mf < 8; ++mf)
#pragma unroll
    for (int p = 0; p < 2; ++p) {
      f32x4 w1 = acc[mf][2 * p];
      f32x4 w2 = acc[mf][2 * p + 1];
      const int j16 = mb * 16 + wm * 8 + mf;
      const int c16 = nbb * 8 + wn * 2 + p;
      size_t qoff = (((size_t)b * 128 + j16) * 32 + c16) * 256 + quad * 64 + l15 * 4;
      bf16x4 qv = *(const bf16x4*)&qs[qoff];
      const int ccol = c16 * 16 + l15;
#pragma unroll
      for (int r = 0; r < 4; ++r) {
        const int j = j16 * 16 + quad * 4 + r;
        out[((size_t)b * 2048 + j) * 512 + ccol] = (float)qv[r] * (w1[r] / w2[r]);
      }
    }
}

extern "C" void kernel_launch(void* const* d_in, const int* in_sizes, int n_in,
                              void* d_out, int out_size, void* d_ws, size_t ws_size,
                              hipStream_t stream) {
  const float* x = (const float*)d_in[0];
  const float* dis = (const float*)d_in[1];
  const float* Wq = (const float*)d_in[2];
  const float* Wk = (const float*)d_in[3];
  const float* Wv = (const float*)d_in[4];
  const float* alpha = (const float*)d_in[5];
  float* out = (float*)d_out;

  char* p = (char*)d_ws;
  bf16_t* x_bf = (bf16_t*)p;  p += (size_t)16384 * 512 * 2;       // 16 MB
  bf16_t* Wall = (bf16_t*)p;  p += (size_t)1536 * 512 * 2;        // 1.5 MB
  bf16_t* kwT  = (bf16_t*)p;  p += (size_t)8 * 512 * 2048 * 2;    // 16 MB
  bf16_t* kwvT = (bf16_t*)p;  p += (size_t)8 * 512 * 2048 * 2;    // 16 MB
  bf16_t* qs_bf = (bf16_t*)p; p += (size_t)16384 * 512 * 2;       // 16 MB (blocked layout)
  if ((size_t)(p - (char*)d_ws) > ws_size) return;  // ws too small: fail visibly

  // 128 KB dynamic LDS for main_gemm (>64 KB needs the opt-in attribute;
  // hipFuncSetAttribute is not a stream op -> graph-capture safe).
  static bool attr_done = false;
  if (!attr_done) {
    hipFuncSetAttribute(reinterpret_cast<const void*>(main_gemm),
                        hipFuncAttributeMaxDynamicSharedMemorySize, 131072);
    attr_done = true;
  }

  cvt_all<<<8960, 256, 0, stream>>>(x, Wq, Wk, Wv, x_bf, Wall);
  proj_dw<<<1536, 256, 0, stream>>>(x_bf, Wall, qs_bf, kwT, kwvT);
  main_gemm<<<256, 512, 131072, stream>>>(dis, kwvT, kwT, qs_bf, alpha, out);
}

// Round 13
// 309.400 us; speedup vs baseline: 1.2563x; 1.2563x over previous
//
#include <hip/hip_runtime.h>
#include <math.h>
#include <stdint.h>

// Problem constants: B=8, N=2048, D=512, H=16, dk=32
// q = x@Wq^T; k = x@Wk^T; v = x@Wv^T            [t=16384, c=512]
// dw[b,i,j] = exp(-alpha*11*dis[b,i,j])
// w1[b,j,c] = sum_i dw[b,i,j]*exp(k)[b,i,c]*v[b,i,c]
// w2[b,j,c] = sum_i dw[b,i,j]*exp(k)[b,i,c]
// out[b,j,c] = sigmoid(q)[b,j,c] * w1/w2
//
// ROUND-13: wholesale revert to the round-8 hardware-verified state (307.8 us).
// The dwT-fusion experiments (r10-r12) were invariant at ~180 us under three
// different schedules — regime not understood, design abandoned per fallback.

typedef __bf16 bf16_t;
typedef __attribute__((ext_vector_type(4))) __bf16 bf16x4;
typedef __attribute__((ext_vector_type(8))) __bf16 bf16x8;
typedef __attribute__((ext_vector_type(4))) float f32x4;

#define MFMA_BF16(a, b, c) __builtin_amdgcn_mfma_f32_16x16x32_bf16((a), (b), (c), 0, 0, 0)

static __device__ __forceinline__ void async_ld16(const bf16_t* g, bf16_t* lds) {
  __builtin_amdgcn_global_load_lds(
      reinterpret_cast<__attribute__((address_space(1))) unsigned int*>(
          reinterpret_cast<uintptr_t>(g)),
      reinterpret_cast<__attribute__((address_space(3))) unsigned int*>(
          reinterpret_cast<uintptr_t>(lds)),
      16, 0, 0);
}

// counted-vmcnt wait (T4). "memory" clobber orders surrounding mem ops; the
// sched_barrier stops hipcc hoisting register-only MFMA past it (rule #18).
#define WAITV(N)                                          \
  do {                                                    \
    asm volatile("s_waitcnt vmcnt(" #N ")" ::: "memory"); \
    __builtin_amdgcn_sched_barrier(0);                    \
  } while (0)

// ---- 3-bit XOR swizzle pair (hardware-validated) ----
// Stage ROWS x 64 bf16 tile: stored[row][pos] holds global chunk (pos ^ (row&7));
// swizzle applied via per-lane SOURCE address, LDS dest stays linear (rule #21).
template <int ROWS>
static __device__ __forceinline__ void stage3(const bf16_t* g, int ldg, bf16_t* lds,
                                              int wv, int lane) {
  const int r_in = lane >> 3;      // 8 chunks per 64-wide row
  const int cpos = lane & 7;
#pragma unroll
  for (int s = 0; s < ROWS / 32; ++s) {
    int rbase = wv * (ROWS / 4) + s * 8;   // multiple of 8 -> row&7 == r_in
    int row = rbase + r_in;
    int cg = cpos ^ (row & 7);
    async_ld16(g + (size_t)row * ldg + cg * 8, lds + rbase * 64 + lane * 8);
  }
}

// Swizzled fragment read (BK=64): logical chunk lc read at pos = lc ^ (row&7).
static __device__ __forceinline__ bf16x8 frag3(const bf16_t* lds, int row16,
                                               int l15, int quad, int kc) {
  int p = (quad | (kc << 2)) ^ (l15 & 7);
  return *(const bf16x8*)&lds[(row16 + l15) * 64 + p * 8];
}

// ---------------- fused fp32 -> bf16 conversion ----------------
__global__ __launch_bounds__(256) void cvt_all(const float* __restrict__ x,
                                               const float* __restrict__ wq,
                                               const float* __restrict__ wk,
                                               const float* __restrict__ wv,
                                               bf16_t* __restrict__ xb,
                                               bf16_t* __restrict__ wall) {
  int i = blockIdx.x * 256 + threadIdx.x;  // f32x4 index
  if (i >= 2293760) return;
  const float* src;
  bf16_t* dst;
  int off;
  if (i < 2097152) {
    src = x; dst = xb; off = i;
  } else {
    int j = i - 2097152;
    int sel = j >> 16;        // 65536 f32x4 per weight
    off = j & 65535;
    src = (sel == 0) ? wq : (sel == 1) ? wk : wv;
    dst = wall + (size_t)sel * 262144;
  }
  f32x4 f = ((const f32x4*)src)[off];
  bf16x4 o;
  o[0] = (bf16_t)f[0]; o[1] = (bf16_t)f[1]; o[2] = (bf16_t)f[2]; o[3] = (bf16_t)f[3];
  ((bf16x4*)dst)[off] = o;
}

// ---------------- merged projection GEMM + dis-weight transpose ----------------
// (round-8 verified: proj paths with 3-bit swizzle; dw path interleaved 16/19)
__global__ __launch_bounds__(256, 4) void proj_dw(const bf16_t* __restrict__ A,
                                                  const bf16_t* __restrict__ W,
                                                  bf16_t* __restrict__ qs,
                                                  bf16_t* __restrict__ kwT,
                                                  bf16_t* __restrict__ kwvT,
                                                  const float* __restrict__ dis,
                                                  bf16_t* __restrict__ dwT,
                                                  const float* __restrict__ alpha) {
  __shared__ __align__(16) char pool[32768];
  const int tid = threadIdx.x;
  const int idx = blockIdx.x;
  const int g19 = idx / 19, r19 = idx % 19;

  if (r19 >= 3) {
    // ---------------- dw path ----------------
    int sub = g19 * 16 + (r19 - 3);
    int jt = sub & 31, it = (sub >> 5) & 31, b = sub >> 10;
    bf16_t* t = (bf16_t*)pool;  // 64*65*2 = 8320 B
    const float coef = -alpha[0] * 11.0f;  // log2(2048) == 11
    const int j0 = jt * 64, i0 = it * 64;
    const int rr = tid >> 4, cc = (tid & 15) * 4;
#pragma unroll
    for (int p = 0; p < 4; ++p) {
      int i = rr + p * 16;
      f32x4 d = *(const f32x4*)&dis[((size_t)(b * 2048 + i0 + i)) * 2048 + j0 + cc];
#pragma unroll
      for (int e = 0; e < 4; ++e) t[(cc + e) * 65 + i] = (bf16_t)__expf(coef * d[e]);
    }
    __syncthreads();
#pragma unroll
    for (int p = 0; p < 4; ++p) {
      int j = rr + p * 16;
      bf16x4 o;
#pragma unroll
      for (int e = 0; e < 4; ++e) o[e] = t[j * 65 + cc + e];
      *(bf16x4*)&dwT[((size_t)(b * 2048 + j0 + j)) * 2048 + i0 + cc] = o;
    }
    return;
  }

  // ---------------- proj path ----------------
  const int sub = g19 * 3 + r19;
  const int m_blk = sub / 12, n_blk = sub % 12;
  bf16_t* As = (bf16_t*)pool;  // 128x64 = 16 KB
  const int K = 512;
  const int wv = tid >> 6, lane = tid & 63;
  const int l15 = lane & 15, quad = lane >> 4;
  const int wm = wv >> 1, wn = wv & 1;
  const bf16_t* Am = A + (size_t)(m_blk * 128) * K;
  const int b = m_blk >> 4;

  if (n_blk < 4) {
    // ---- q path: 128x128 tile, 64x64 wave tiles, BK=64 ----
    bf16_t* Bsq = (bf16_t*)(pool + 16384);  // 128x64 = 16 KB
    const int c_loc = n_blk * 128;
    f32x4 acc[4][4];
#pragma unroll
    for (int a = 0; a < 4; ++a)
#pragma unroll
      for (int c = 0; c < 4; ++c) acc[a][c] = (f32x4){0.f, 0.f, 0.f, 0.f};

    for (int k0 = 0; k0 < K; k0 += 64) {
      stage3<128>(Am + k0, K, As, wv, lane);
      stage3<128>(W + (size_t)c_loc * K + k0, K, Bsq, wv, lane);
      __syncthreads();
#pragma unroll
      for (int kc = 0; kc < 2; ++kc) {
        bf16x8 a[4], bb[4];
#pragma unroll
        for (int mf = 0; mf < 4; ++mf) a[mf] = frag3(As, wm * 64 + mf * 16, l15, quad, kc);
#pragma unroll
        for (int nf = 0; nf < 4; ++nf) bb[nf] = frag3(Bsq, wn * 64 + nf * 16, l15, quad, kc);
#pragma unroll
        for (int mf = 0; mf < 4; ++mf)
#pragma unroll
          for (int nf = 0; nf < 4; ++nf) acc[mf][nf] = MFMA_BF16(a[mf], bb[nf], acc[mf][nf]);
      }
      __syncthreads();
    }
#pragma unroll
    for (int mf = 0; mf < 4; ++mf)
#pragma unroll
      for (int nf = 0; nf < 4; ++nf) {
        int j16 = (m_blk & 15) * 8 + wm * 4 + mf;
        int c16 = n_blk * 8 + wn * 4 + nf;
        bf16x4 o;
#pragma unroll
        for (int r = 0; r < 4; ++r)
          o[r] = (bf16_t)(1.0f / (1.0f + __expf(-acc[mf][nf][r])));
        size_t off = (((size_t)b * 128 + j16) * 32 + c16) * 256 + quad * 64 + l15 * 4;
        *(bf16x4*)&qs[off] = o;
      }
  } else {
    // ---- kv path: 128x64 tile, 64x32 wave tiles, k and v share A staging, BK=64 ----
    bf16_t* Bk = (bf16_t*)(pool + 16384);  // 64x64 = 8 KB
    bf16_t* Bv = (bf16_t*)(pool + 24576);  // 64x64 = 8 KB
    const int c_loc = (n_blk - 4) * 64;
    f32x4 acck[4][2], accv[4][2];
#pragma unroll
    for (int a = 0; a < 4; ++a)
#pragma unroll
      for (int c = 0; c < 2; ++c) {
        acck[a][c] = (f32x4){0.f, 0.f, 0.f, 0.f};
        accv[a][c] = (f32x4){0.f, 0.f, 0.f, 0.f};
      }
    const bf16_t* Wk = W + (size_t)(512 + c_loc) * K;
    const bf16_t* Wv = W + (size_t)(1024 + c_loc) * K;

    for (int k0 = 0; k0 < K; k0 += 64) {
      stage3<128>(Am + k0, K, As, wv, lane);
      stage3<64>(Wk + k0, K, Bk, wv, lane);
      stage3<64>(Wv + k0, K, Bv, wv, lane);
      __syncthreads();
#pragma unroll
      for (int kc = 0; kc < 2; ++kc) {
        bf16x8 a[4], bk[2], bv[2];
#pragma unroll
        for (int mf = 0; mf < 4; ++mf) a[mf] = frag3(As, wm * 64 + mf * 16, l15, quad, kc);
#pragma unroll
        for (int nf = 0; nf < 2; ++nf) {
          bk[nf] = frag3(Bk, wn * 32 + nf * 16, l15, quad, kc);
          bv[nf] = frag3(Bv, wn * 32 + nf * 16, l15, quad, kc);
        }
#pragma unroll
        for (int mf = 0; mf < 4; ++mf)
#pragma unroll
          for (int nf = 0; nf < 2; ++nf) {
            acck[mf][nf] = MFMA_BF16(a[mf], bk[nf], acck[mf][nf]);
            accv[mf][nf] = MFMA_BF16(a[mf], bv[nf], accv[mf][nf]);
          }
      }
      __syncthreads();
    }

    // epilogue: exp/mul + 32-c-chunk transpose through aliased LDS
    bf16_t* Lk = (bf16_t*)pool;            // 32 x 136 = 8704 B
    bf16_t* Lv = (bf16_t*)(pool + 8704);   // 32 x 136 = 8704 B
    const int t0 = (m_blk * 128) & 2047;
#pragma unroll
    for (int ci = 0; ci < 2; ++ci) {
      if (wn == ci) {
#pragma unroll
        for (int mf = 0; mf < 4; ++mf)
#pragma unroll
          for (int nf = 0; nf < 2; ++nf) {
            int cl = nf * 16 + l15;
            int tl = wm * 64 + mf * 16 + quad * 4;
#pragma unroll
            for (int r = 0; r < 4; ++r) {
              float kw = __expf(acck[mf][nf][r]);
              Lk[cl * 136 + tl + r] = (bf16_t)kw;
              Lv[cl * 136 + tl + r] = (bf16_t)(kw * accv[mf][nf][r]);
            }
          }
      }
      __syncthreads();
      {
        int rowt = tid >> 3, colt = (tid & 7) * 16;
        int c = c_loc + ci * 32 + rowt;
        size_t g = ((size_t)b * 512 + c) * 2048 + t0 + colt;
        *(bf16x8*)&kwT[g] = *(const bf16x8*)&Lk[rowt * 136 + colt];
        *(bf16x8*)&kwT[g + 8] = *(const bf16x8*)&Lk[rowt * 136 + colt + 8];
        *(bf16x8*)&kwvT[g] = *(const bf16x8*)&Lv[rowt * 136 + colt];
        *(bf16x8*)&kwvT[g + 8] = *(const bf16x8*)&Lv[rowt * 136 + colt + 8];
      }
      __syncthreads();
    }
  }
}

// ---------------- main batched GEMM + fused epilogue ----------------
// 256^2 / 8-wave (2M x 4N) / BK=64 / 4 phases / 2 x 64 KB LDS buffers.
// T4 counted vmcnt (round-8 hardware-verified; main_gemm 90.7 -> <78.6 us).
__global__ __launch_bounds__(512, 2) void main_gemm(const bf16_t* __restrict__ dwT,
                                                    const bf16_t* __restrict__ kwvT,
                                                    const bf16_t* __restrict__ kwT,
                                                    const bf16_t* __restrict__ qs,
                                                    float* __restrict__ out) {
  extern __shared__ __align__(16) char smem_raw[];
  bf16_t* const lds = (bf16_t*)smem_raw;  // [2 buf][A 16384 | B 16384] elements
  const int K = 2048;
  const int tid = threadIdx.x;
  const int wv = tid >> 6, lane = tid & 63;
  const int l15 = lane & 15, quad = lane >> 4;
  const int bi = blockIdx.x;
  const int b = bi & 7, nbb = (bi >> 3) & 3, mb = bi >> 5;
  const int wm = wv >> 2, wn = wv & 3;       // 2 m-waves x 4 n-waves
  const int r_in = lane >> 3, cpos = lane & 7;
  const int cg = cpos ^ r_in;                // 3-bit swizzled source chunk (row&7 == r_in)

  const bf16_t* const Ab = dwT + ((size_t)b * 2048 + mb * 256) * K;
  const bf16_t* const BvB = kwvT + (size_t)b * 512 * K;
  const bf16_t* const BkB = kwT + (size_t)b * 512 * K;

  // A chunks s=0..3: rows s*64 + wv*8 + r_in (read order: s0,s2 then s1,s3).
  const bf16_t* aSrc[4];
  int aDst[4];
#pragma unroll
  for (int s = 0; s < 4; ++s) {
    const int row = s * 64 + wv * 8 + r_in;
    aSrc[s] = Ab + (size_t)row * K + cg * 8;
    aDst[s] = s * 4096 + wv * 512 + lane * 8;
  }
  // B chunks cb=0..3 = read-order quarters of the interleaved B rows:
  const bf16_t* bSrc[4];
  int bDst[4];
#pragma unroll
  for (int cb = 0; cb < 4; ++cb) {
    const int base1 = (cb & 1) * 128 + (cb >> 1) * 32;
    const int rowbase = base1 + (wv >> 2) * 64 + (wv & 3) * 8;
    const int row = rowbase + r_in;            // row&7 == r_in (bases mult. of 8)
    const int type = (row >> 4) & 1;           // 0 -> kwv (w1), 1 -> kw (w2)
    const int crow = nbb * 128 + (row >> 5) * 16 + (row & 15);
    bSrc[cb] = (type ? BkB : BvB) + (size_t)crow * K + cg * 8;
    bDst[cb] = 16384 + rowbase * 64 + lane * 8;
  }

  f32x4 acc[8][4];
#pragma unroll
  for (int m = 0; m < 8; ++m)
#pragma unroll
    for (int n = 0; n < 4; ++n) acc[m][n] = (f32x4){0.f, 0.f, 0.f, 0.f};

  bf16x8 a[8];   // current A m-half: [mf*2+kc]
  bf16x8 b0[4];  // B n-half 0: [nf*2+kc]
  bf16x8 b1[4];  // B n-half 1

#define STAGE_A(dst, s, koff) async_ld16(aSrc[s] + (koff), lds + (dst)*32768 + aDst[s])
#define STAGE_B(dst, cb, koff) async_ld16(bSrc[cb] + (koff), lds + (dst)*32768 + bDst[cb])

#define LOADA(As_, mh)                                                             \
  do {                                                                             \
    _Pragma("unroll") for (int mf = 0; mf < 4; ++mf)                               \
        _Pragma("unroll") for (int kc = 0; kc < 2; ++kc)                           \
            a[mf * 2 + kc] =                                                       \
        frag3((As_), wm * 128 + (mh)*64 + mf * 16, l15, quad, kc);                 \
  } while (0)

#define LOADB(Bs_, dstarr, nh)                                                     \
  do {                                                                             \
    _Pragma("unroll") for (int nf = 0; nf < 2; ++nf)                               \
        _Pragma("unroll") for (int kc = 0; kc < 2; ++kc)                           \
            dstarr[nf * 2 + kc] =                                                  \
        frag3((Bs_), wn * 64 + (nh)*32 + nf * 16, l15, quad, kc);                  \
  } while (0)

#define MFMA_PH(mh, nh, barr)                                                      \
  do {                                                                             \
    __builtin_amdgcn_s_setprio(1);                                                 \
    _Pragma("unroll") for (int kc = 0; kc < 2; ++kc)                               \
        _Pragma("unroll") for (int mf = 0; mf < 4; ++mf)                           \
            _Pragma("unroll") for (int nf = 0; nf < 2; ++nf)                       \
                acc[(mh)*4 + mf][(nh)*2 + nf] =                                    \
        MFMA_BF16(a[mf * 2 + kc], barr[nf * 2 + kc], acc[(mh)*4 + mf][(nh)*2 + nf]); \
    __builtin_amdgcn_s_setprio(0);                                                 \
  } while (0)

  // prologue: tile 0's 8 chunks in read order; publish first 4, keep 4 in flight.
  STAGE_A(0, 0, 0); STAGE_A(0, 2, 0); STAGE_B(0, 0, 0); STAGE_B(0, 1, 0);
  STAGE_B(0, 2, 0); STAGE_B(0, 3, 0); STAGE_A(0, 1, 0); STAGE_A(0, 3, 0);
  WAITV(4);
  __builtin_amdgcn_s_barrier();

  for (int t = 0; t < 32; ++t) {
    const int c = t & 1;
    const int nx = c ^ 1;
    const bf16_t* As_c = lds + c * 32768;
    const bf16_t* Bs_c = As_c + 16384;
    const int ko = (t + 1) * 64;
    // phase 0: issue t+1's first-read chunks; compute (m0,n0)
    if (t < 31) { STAGE_A(nx, 0, ko); STAGE_A(nx, 2, ko); STAGE_B(nx, 0, ko); STAGE_B(nx, 1, ko); }
    LOADA(As_c, 0);
    LOADB(Bs_c, b0, 0);
    __builtin_amdgcn_s_barrier();
    MFMA_PH(0, 0, b0);
    WAITV(6);                       // publish this tile's B2',B3'
    __builtin_amdgcn_s_barrier();
    // phase 1: issue t+1's B2',B3'; compute (m0,n1)
    if (t < 31) { STAGE_B(nx, 2, ko); STAGE_B(nx, 3, ko); }
    LOADB(Bs_c, b1, 1);
    __builtin_amdgcn_s_barrier();
    MFMA_PH(0, 1, b1);
    WAITV(6);                       // publish this tile's A1,A3
    __builtin_amdgcn_s_barrier();
    // phase 2: issue t+1's A1,A3; compute (m1,n1)
    if (t < 31) { STAGE_A(nx, 1, ko); STAGE_A(nx, 3, ko); }
    LOADA(As_c, 1);
    __builtin_amdgcn_s_barrier();
    MFMA_PH(1, 1, b1);
    __builtin_amdgcn_s_barrier();
    // phase 3: compute (m1,n0) from registers; counted boundary publish
    MFMA_PH(1, 0, b0);
    if (t < 30) {
      WAITV(4);                     // publish t+1's first 4 chunks; 4 stay in flight
      __builtin_amdgcn_s_barrier();
    } else if (t == 30) {
      WAITV(0);                     // tail drain: all of tile 31 resident
      __builtin_amdgcn_s_barrier();
    }
  }

#undef STAGE_A
#undef STAGE_B
#undef LOADA
#undef LOADB
#undef MFMA_PH

  // epilogue: nf even = w1 (kwv), nf odd = w2 (kw); pair in registers.
#pragma unroll
  for (int mf = 0; mf < 8; ++mf)
#pragma unroll
    for (int p = 0; p < 2; ++p) {
      f32x4 w1 = acc[mf][2 * p];
      f32x4 w2 = acc[mf][2 * p + 1];
      const int j16 = mb * 16 + wm * 8 + mf;
      const int c16 = nbb * 8 + wn * 2 + p;
      size_t qoff = (((size_t)b * 128 + j16) * 32 + c16) * 256 + quad * 64 + l15 * 4;
      bf16x4 qv = *(const bf16x4*)&qs[qoff];
      const int ccol = c16 * 16 + l15;
#pragma unroll
      for (int r = 0; r < 4; ++r) {
        const int j = j16 * 16 + quad * 4 + r;
        out[((size_t)b * 2048 + j) * 512 + ccol] = (float)qv[r] * (w1[r] / w2[r]);
      }
    }
}

extern "C" void kernel_launch(void* const* d_in, const int* in_sizes, int n_in,
                              void* d_out, int out_size, void* d_ws, size_t ws_size,
                              hipStream_t stream) {
  const float* x = (const float*)d_in[0];
  const float* dis = (const float*)d_in[1];
  const float* Wq = (const float*)d_in[2];
  const float* Wk = (const float*)d_in[3];
  const float* Wv = (const float*)d_in[4];
  const float* alpha = (const float*)d_in[5];
  float* out = (float*)d_out;

  char* p = (char*)d_ws;
  bf16_t* x_bf = (bf16_t*)p;  p += (size_t)16384 * 512 * 2;       // 16 MB
  bf16_t* Wall = (bf16_t*)p;  p += (size_t)1536 * 512 * 2;        // 1.5 MB
  bf16_t* kwT  = (bf16_t*)p;  p += (size_t)8 * 512 * 2048 * 2;    // 16 MB
  bf16_t* kwvT = (bf16_t*)p;  p += (size_t)8 * 512 * 2048 * 2;    // 16 MB
  bf16_t* dwT  = (bf16_t*)p;  p += (size_t)8 * 2048 * 2048 * 2;   // 64 MB
  bf16_t* qs_bf = (bf16_t*)p; p += (size_t)16384 * 512 * 2;       // 16 MB (blocked layout)
  if ((size_t)(p - (char*)d_ws) > ws_size) return;  // ws too small: fail visibly

  // 128 KB dynamic LDS for main_gemm (>64 KB needs the opt-in attribute;
  // hipFuncSetAttribute is not a stream op -> graph-capture safe).
  static bool attr_done = false;
  if (!attr_done) {
    hipFuncSetAttribute(reinterpret_cast<const void*>(main_gemm),
                        hipFuncAttributeMaxDynamicSharedMemorySize, 131072);
    attr_done = true;
  }

  cvt_all<<<8960, 256, 0, stream>>>(x, Wq, Wk, Wv, x_bf, Wall);
  proj_dw<<<9728, 256, 0, stream>>>(x_bf, Wall, qs_bf, kwT, kwvT, dis, dwT, alpha);
  main_gemm<<<256, 512, 131072, stream>>>(dwT, kwvT, kwT, qs_bf, out);
}